// Round 1
// baseline (169.625 us; speedup 1.0000x reference)
//
#include <hip/hip_runtime.h>

#define NB 8
#define ND 32
#define NHW (512*512)
#define NK 16
#define IGN 255

// per-image workspace layout (floats)
#define WS_S   1088
#define O_CNT  0      // counts[16]
#define O_VPIX 16     // # of valid (mask & !=IGN) pixels, incl. out-of-range ids
#define O_SUM  32     // sums[16*32]
#define O_CEN  544    // centers[16*32]
#define O_PULL 1056   // pull partial sums[16]
#define O_PUSH 1072
#define O_REG  1073
#define O_VB   1074
#define O_NID  1075

#define CHUNKS 256
#define TPB 256
#define PIXPB (NHW / CHUNKS)    // 1024
#define ITERS (PIXPB / TPB)     // 4

__global__ __launch_bounds__(256) void k_zero(float* __restrict__ ws) {
    int i = blockIdx.x * blockDim.x + threadIdx.x;
    if (i < NB * WS_S) ws[i] = 0.f;
}

__global__ __launch_bounds__(TPB) void k_accum(const float* __restrict__ pred,
                                               const int* __restrict__ inst,
                                               const unsigned char* __restrict__ msk,
                                               float* __restrict__ ws) {
    __shared__ float lsum[NK][ND + 1];   // +1 pad: segment addrs hit distinct banks
    __shared__ float lcnt[NK];
    __shared__ float lvp;
    const int tid = threadIdx.x;
    const int b = blockIdx.y;
    const int chunk = blockIdx.x;

    for (int i = tid; i < NK * (ND + 1); i += TPB) lsum[i / (ND + 1)][i % (ND + 1)] = 0.f;
    if (tid < NK) lcnt[tid] = 0.f;
    if (tid == 0) lvp = 0.f;
    __syncthreads();

    const float* pb = pred + (size_t)b * ND * NHW;
    const int base = chunk * PIXPB;
    for (int it = 0; it < ITERS; ++it) {
        const int pix = base + it * TPB + tid;
        const int id = inst[(size_t)b * NHW + pix];
        const bool m = (msk[(size_t)b * NHW + pix] != 0) && (id != IGN);
        unsigned long long bal = __ballot(m);
        if ((tid & 63) == 0) atomicAdd(&lvp, (float)__popcll(bal));
        if (m && (unsigned)id < NK) {
            atomicAdd(&lcnt[id], 1.f);
            #pragma unroll
            for (int d = 0; d < ND; ++d) {
                float v = pb[(size_t)d * NHW + pix];
                atomicAdd(&lsum[id][d], v);
            }
        }
    }
    __syncthreads();

    float* wb = ws + b * WS_S;
    for (int i = tid; i < NK * ND; i += TPB)
        atomicAdd(&wb[O_SUM + i], lsum[i / ND][i % ND]);
    if (tid < NK) atomicAdd(&wb[O_CNT + tid], lcnt[tid]);
    if (tid == 0) atomicAdd(&wb[O_VPIX], lvp);
}

__global__ __launch_bounds__(256) void k_centers(float* __restrict__ ws) {
    __shared__ float lc[NK][ND + 1];
    __shared__ float lcnt[NK];
    __shared__ float rsum[256], rcnt[256];
    const int tid = threadIdx.x;
    float* wb = ws + blockIdx.x * WS_S;

    if (tid < NK) lcnt[tid] = wb[O_CNT + tid];
    __syncthreads();
    for (int i = tid; i < NK * ND; i += 256) {
        int k = i / ND, d = i % ND;
        float c = wb[O_SUM + i] / fmaxf(lcnt[k], 1.f);
        lc[k][d] = c;
        wb[O_CEN + i] = c;
    }
    __syncthreads();

    // push: 256 ordered pairs, one per thread
    const int i = tid >> 4, j = tid & 15;
    const bool pm = (i != j) && (lcnt[i] > 0.f) && (lcnt[j] > 0.f);
    float sq = 0.f;
    #pragma unroll
    for (int d = 0; d < ND; ++d) { float df = lc[i][d] - lc[j][d]; sq += df * df; }
    float dm = sqrtf(pm ? sq : 1.f);
    float r = fmaxf(2.f * 1.5f - dm, 0.f);
    rsum[tid] = pm ? r * r : 0.f;
    rcnt[tid] = pm ? 1.f : 0.f;
    __syncthreads();
    for (int s = 128; s > 0; s >>= 1) {
        if (tid < s) { rsum[tid] += rsum[tid + s]; rcnt[tid] += rcnt[tid + s]; }
        __syncthreads();
    }

    if (tid == 0) {
        float nids = 0.f;
        for (int k = 0; k < NK; ++k) nids += (lcnt[k] > 0.f) ? 1.f : 0.f;
        float npairs = rcnt[0];
        float push = (nids > 1.f) ? rsum[0] / fmaxf(npairs, 1.f) : 0.f;
        float reg = 0.f;
        for (int k = 0; k < NK; ++k) {
            if (lcnt[k] > 0.f) {
                float cs = 0.f;
                for (int d = 0; d < ND; ++d) cs += lc[k][d] * lc[k][d];
                reg += sqrtf(cs);
            }
        }
        reg /= fmaxf(nids, 1.f);
        wb[O_PUSH] = push;
        wb[O_REG] = reg;
        wb[O_VB] = (wb[O_VPIX] > 0.f) ? 1.f : 0.f;
        wb[O_NID] = nids;
    }
}

__global__ __launch_bounds__(TPB) void k_pull(const float* __restrict__ pred,
                                              const int* __restrict__ inst,
                                              const unsigned char* __restrict__ msk,
                                              float* __restrict__ ws) {
    __shared__ float lc[NK][ND + 1];   // pad -> conflict-free center reads
    __shared__ float lp[NK];
    const int tid = threadIdx.x;
    // reversed global order vs k_accum: tail of pass-1 stream is L3-resident
    const int b = NB - 1 - blockIdx.y;
    const int chunk = CHUNKS - 1 - blockIdx.x;
    float* wb = ws + b * WS_S;

    for (int i = tid; i < NK * ND; i += TPB) lc[i / ND][i % ND] = wb[O_CEN + i];
    if (tid < NK) lp[tid] = 0.f;
    __syncthreads();

    const float* pb = pred + (size_t)b * ND * NHW;
    const int base = chunk * PIXPB;
    for (int it = ITERS - 1; it >= 0; --it) {
        const int pix = base + it * TPB + tid;
        const int id = inst[(size_t)b * NHW + pix];
        const bool m = (msk[(size_t)b * NHW + pix] != 0) && (id != IGN) && ((unsigned)id < NK);
        if (m) {
            float sq = 0.f;
            #pragma unroll
            for (int d = 0; d < ND; ++d) {
                float v = pb[(size_t)d * NHW + pix];
                float df = v - lc[id][d];
                sq += df * df;
            }
            float dist = sqrtf(sq);
            float r = fmaxf(dist - 0.5f, 0.f);
            atomicAdd(&lp[id], r * r);
        }
    }
    __syncthreads();
    if (tid < NK) atomicAdd(&wb[O_PULL + tid], lp[tid]);
}

__global__ void k_final(const float* __restrict__ ws, float* __restrict__ out) {
    const int tid = threadIdx.x;  // 64 threads, lanes 0..7 carry images
    float contrib = 0.f, vb = 0.f;
    if (tid < NB) {
        const float* wb = ws + tid * WS_S;
        float nids = wb[O_NID];
        float pull = 0.f;
        for (int k = 0; k < NK; ++k) {
            float c = wb[O_CNT + k];
            if (c > 0.f) pull += wb[O_PULL + k] / fmaxf(c, 1.f);
        }
        pull /= fmaxf(nids, 1.f);
        vb = wb[O_VB];
        contrib = (pull + wb[O_PUSH] + 0.001f * wb[O_REG]) * vb;
    }
    #pragma unroll
    for (int off = 32; off > 0; off >>= 1) {
        contrib += __shfl_down(contrib, off);
        vb += __shfl_down(vb, off);
    }
    if (tid == 0) out[0] = (vb > 0.f) ? contrib / fmaxf(vb, 1.f) : 0.f;
}

extern "C" void kernel_launch(void* const* d_in, const int* in_sizes, int n_in,
                              void* d_out, int out_size, void* d_ws, size_t ws_size,
                              hipStream_t stream) {
    const float* pred = (const float*)d_in[0];
    const int* inst = (const int*)d_in[1];
    const unsigned char* msk = (const unsigned char*)d_in[2];
    float* out = (float*)d_out;
    float* ws = (float*)d_ws;

    k_zero<<<(NB * WS_S + 255) / 256, 256, 0, stream>>>(ws);
    dim3 grid(CHUNKS, NB);
    k_accum<<<grid, TPB, 0, stream>>>(pred, inst, msk, ws);
    k_centers<<<NB, 256, 0, stream>>>(ws);
    k_pull<<<grid, TPB, 0, stream>>>(pred, inst, msk, ws);
    k_final<<<1, 64, 0, stream>>>(ws, out);
}